// Round 11
// baseline (381.162 us; speedup 1.0000x reference)
//
#include <hip/hip_runtime.h>
#include <math.h>

#define H_IMG 224
#define W_IMG 224
#define HW (H_IMG * W_IMG)
#define EPSF 1e-8f
#define NV 6890
#define NF 13776
#define NB 2
#define FCHUNK 128
#define NCHUNK ((NF + FCHUNK - 1) / FCHUNK)   // 108
#define FPAD (NCHUNK * FCHUNK)                // 13824
#define NSPLIT 4
#define NBUCK 1024
#define CHDR_STRIDE 128
#define KEY_INIT 0x7F800000FFFFFFFFULL        // zp=+inf, idx=~0

// workspace byte offsets (256-aligned)
#define OFF_VERTS 0u                          // NB*NV*16      = 220,480
#define OFF_ZBU   220672u                     // NB*NF*4       = 110,208
#define OFF_ZBS   331008u                     // NB*FPAD*4     = 110,592
#define OFF_BBS   441600u                     // NB*FPAD*16    = 442,368
#define OFF_GMS   883968u                     // NB*FPAD*64    = 1,769,472
#define OFF_OIS   2653440u                    // NB*FPAD*4     = 110,592
#define OFF_INV   2764032u                    // NB*NF*4       = 110,208
#define OFF_CHDR  2874368u                    // NB*128*4      = 1,024
#define OFF_CNT   2875392u                    // NB*1024*4     = 8,192
#define OFF_OFFS  2883584u                    // NB*1024*4     = 8,192
#define OFF_KEY   2891776u                    // NB*HW*8       = 802,816  (end ~3.69 MB)

__device__ inline unsigned long long shfl_xor_u64(unsigned long long v, int m) {
  unsigned lo = (unsigned)v, hi = (unsigned)(v >> 32);
  lo = __shfl_xor(lo, m);
  hi = __shfl_xor(hi, m);
  return ((unsigned long long)hi << 32) | lo;
}

// Projection fused with all buffer inits (one launch, grid covers NB*HW).
__global__ void proj_init_kernel(const float* __restrict__ v,
                                 const float* __restrict__ cf,
                                 const float* __restrict__ cc,
                                 const float* __restrict__ ct,
                                 const float* __restrict__ crt,
                                 float4* __restrict__ verts,
                                 unsigned long long* __restrict__ keybuf,
                                 float* __restrict__ zbS, float4* __restrict__ bbS,
                                 unsigned* __restrict__ chdr, unsigned* __restrict__ cnt) {
  int i = blockIdx.x * blockDim.x + threadIdx.x;
  if (i < NB * NV) {
    float r0 = crt[0], r1 = crt[1], r2 = crt[2];
    float ss = __fadd_rn(__fadd_rn(__fmul_rn(r0, r0), __fmul_rn(r1, r1)), __fmul_rn(r2, r2));
    float th = sqrtf(__fadd_rn(ss, 1e-12f));
    float kx = r0 / th, ky = r1 / th, kz = r2 / th;
    float c = cosf(th), s = sinf(th), oc = 1.0f - c;
    float R00 = c + oc * kx * kx,      R01 = oc * kx * ky - s * kz, R02 = oc * kx * kz + s * ky;
    float R10 = oc * ky * kx + s * kz, R11 = c + oc * ky * ky,      R12 = oc * ky * kz - s * kx;
    float R20 = oc * kz * kx - s * ky, R21 = oc * kz * ky + s * kx, R22 = c + oc * kz * kz;
    float x = v[i * 3 + 0], y = v[i * 3 + 1], z = v[i * 3 + 2];
    float xc = R00 * x + R01 * y + R02 * z + ct[0];
    float yc = R10 * x + R11 * y + R12 * z + ct[1];
    float zc = R20 * x + R21 * y + R22 * z + ct[2];
    float zs = fmaxf(zc, EPSF);
    float u = __fadd_rn(__fmul_rn(xc / zs, cf[0]), cc[0]);
    float w = __fadd_rn(__fmul_rn(yc / zs, cf[1]), cc[1]);
    verts[i] = make_float4(u, w, zc, 0.0f);
  }
  if (i < NB * HW) keybuf[i] = KEY_INIT;
  if (i < NB * FPAD) {
    zbS[i] = 3e30f;                                      // pad: sorts last
    bbS[i] = make_float4(1e30f, -1e30f, 1e30f, -1e30f);  // always-miss -> prefilter kills
  }
  if (i < NB * CHDR_STRIDE) chdr[i] = 0x7F800000u;       // +inf bits
  if (i < NB * NBUCK) cnt[i] = 0u;
}

// Depth lower-bound per face + bucket histogram.
// zb <= zp guaranteed: zp = 1/(sum b_i/z_i) >= minz/(1+serr), serr ~ 3*werr/|area|
// with werr ~5 ulps of the largest edge-function product term. Tight bound
// (slack 1e-3) only when 3*werr <= 5e-4*|area|; else zb=0 (never depth-culled).
__global__ void zb_kernel(const int* __restrict__ f, const float4* __restrict__ verts,
                          float* __restrict__ zbU, unsigned* __restrict__ cnt) {
  int i = blockIdx.x * blockDim.x + threadIdx.x;
  if (i >= NB * NF) return;
  int b = i / NF, fi = i - b * NF;
  int i0 = f[fi * 3 + 0], i1 = f[fi * 3 + 1], i2 = f[fi * 3 + 2];
  float4 p0 = verts[b * NV + i0], p1 = verts[b * NV + i1], p2 = verts[b * NV + i2];
  float area = __fsub_rn(__fmul_rn(__fsub_rn(p1.x, p0.x), __fsub_rn(p2.y, p0.y)),
                         __fmul_rn(__fsub_rn(p1.y, p0.y), __fsub_rn(p2.x, p0.x)));
  bool nz = fabsf(area) > EPSF;
  bool zv = (p0.z > EPSF) && (p1.z > EPSF) && (p2.z > EPSF);
  bool ok = nz && zv;
  float zb;
  if (!ok) {
    zb = 3e30f;  // invalid: can never produce a hit (inv_z <= EPS); sorts last
  } else {
    float minz = fminf(fminf(fmaxf(p0.z, EPSF), fmaxf(p1.z, EPSF)), fmaxf(p2.z, EPSF));
    float M = fmaxf(fmaxf(fmaxf(fabsf(p0.x), fabsf(p0.y)), fmaxf(fabsf(p1.x), fabsf(p1.y))),
                    fmaxf(fabsf(p2.x), fabsf(p2.y)));
    float werr = (2.0f * M) * (M + 256.0f) * 6e-7f;
    bool tight = (3.0f * werr) <= (5e-4f * fabsf(area));
    zb = tight ? __fmul_rn(minz, 0.999f) : 0.0f;
  }
  zbU[i] = zb;
  int bucket = (int)fminf(fmaxf(zb * 256.0f, 0.0f), (float)(NBUCK - 1));
  atomicAdd(&cnt[b * NBUCK + bucket], 1u);
}

// Shfl-based exclusive scan over 1024 buckets (2 barriers, no 10-round ladder).
__global__ __launch_bounds__(1024) void scan_kernel(const unsigned* __restrict__ cnt,
                                                    unsigned* __restrict__ offs) {
  __shared__ unsigned wsum[16];
  int t = threadIdx.x, b = blockIdx.x;
  int lane = t & 63, wid = t >> 6;
  unsigned v = cnt[b * NBUCK + t];
  unsigned acc = v;
  #pragma unroll
  for (int d = 1; d < 64; d <<= 1) {
    unsigned n = __shfl_up(acc, d);
    if (lane >= d) acc += n;
  }
  if (lane == 63) wsum[wid] = acc;
  __syncthreads();
  if (t < 16) {
    unsigned wv = wsum[t];
    #pragma unroll
    for (int d = 1; d < 16; d <<= 1) {
      unsigned n = __shfl_up(wv, d, 16);
      if (t >= d) wv += n;
    }
    wsum[t] = wv;
  }
  __syncthreads();
  unsigned base = (wid > 0) ? wsum[wid - 1] : 0u;
  offs[b * NBUCK + t] = base + acc - v;  // exclusive
}

// Scatter into depth-sorted SoA. Record values use the exact reference fp32 op
// sequence -> bit-identical results regardless of within-bucket position.
__global__ void scatter_kernel(const int* __restrict__ f, const float4* __restrict__ verts,
                               const float* __restrict__ zbU, unsigned* __restrict__ offs,
                               float* __restrict__ zbS, float4* __restrict__ bbS,
                               float4* __restrict__ gmS, int* __restrict__ oiS,
                               int* __restrict__ inv, unsigned* __restrict__ chdr) {
  int i = blockIdx.x * blockDim.x + threadIdx.x;
  if (i >= NB * NF) return;
  int b = i / NF, fi = i - b * NF;
  float zb = zbU[i];
  int bucket = (int)fminf(fmaxf(zb * 256.0f, 0.0f), (float)(NBUCK - 1));
  unsigned pos = atomicAdd(&offs[b * NBUCK + bucket], 1u);
  int i0 = f[fi * 3 + 0], i1 = f[fi * 3 + 1], i2 = f[fi * 3 + 2];
  float4 p0 = verts[b * NV + i0], p1 = verts[b * NV + i1], p2 = verts[b * NV + i2];
  float x0 = p0.x, y0 = p0.y, z0 = p0.z;
  float x1 = p1.x, y1 = p1.y, z1 = p1.z;
  float x2 = p2.x, y2 = p2.y, z2 = p2.z;
  float area = __fsub_rn(__fmul_rn(__fsub_rn(x1, x0), __fsub_rn(y2, y0)),
                         __fmul_rn(__fsub_rn(y1, y0), __fsub_rn(x2, x0)));
  bool nz = fabsf(area) > EPSF;
  float inv_area = nz ? (1.0f / area) : 0.0f;
  bool zv = (z0 > EPSF) && (z1 > EPSF) && (z2 > EPSF);
  bool ok = nz && zv;
  float zz0 = ok ? fmaxf(z0, EPSF) : 1e30f;
  float zz1 = ok ? fmaxf(z1, EPSF) : 1e30f;
  float zz2 = ok ? fmaxf(z2, EPSF) : 1e30f;
  size_t sp_ = (size_t)b * FPAD + pos;
  zbS[sp_] = zb;
  bbS[sp_] = make_float4(fminf(fminf(x0, x1), x2), fmaxf(fmaxf(x0, x1), x2),
                         fminf(fminf(y0, y1), y2), fmaxf(fmaxf(y0, y1), y2));
  gmS[sp_ * 4 + 0] = make_float4(__fsub_rn(x2, x1), __fsub_rn(y2, y1), x1, y1);
  gmS[sp_ * 4 + 1] = make_float4(__fsub_rn(x0, x2), __fsub_rn(y0, y2), x2, y2);
  gmS[sp_ * 4 + 2] = make_float4(__fsub_rn(x1, x0), __fsub_rn(y1, y0), x0, y0);
  gmS[sp_ * 4 + 3] = make_float4(zz0, zz1, zz2, inv_area);
  oiS[sp_] = fi;
  inv[i] = (int)pos;
  atomicMin(&chdr[b * CHDR_STRIDE + (int)(pos / FCHUNK)], __float_as_uint(zb));
}

// Suffix-min over chunk headers: chdr[c] := min over chunks >= c (uint min is
// order-preserving for nonnegative floats) -> raster break is conservative.
__global__ __launch_bounds__(CHDR_STRIDE) void suffix_kernel(unsigned* __restrict__ chdr) {
  __shared__ unsigned s[CHDR_STRIDE];
  int t = threadIdx.x, b = blockIdx.x;
  s[t] = chdr[b * CHDR_STRIDE + t];
  __syncthreads();
  for (int d = 1; d < CHDR_STRIDE; d <<= 1) {
    unsigned v = (t + d < CHDR_STRIDE) ? s[t + d] : 0x7F800000u;
    __syncthreads();
    s[t] = (v < s[t]) ? v : s[t];
    __syncthreads();
  }
  chdr[b * CHDR_STRIDE + t] = s[t];
}

// Block = 256 threads = 4 independent waves; each wave owns a 4x4 pixel tile
// (16 pixels x 4 face-slots). NSPLIT=4 blocks per tile scan interleaved chunk
// subsequences (c = sp, sp+4, ...) and merge via keybuf atomicMin — fixes the
// heavy-tile tail (load imbalance). Prefilter per 64-face half-chunk: lane
// loads its face's zb AND bbox (coalesced); pass = depth && bbox-overlaps-tile;
// one __ballot -> candidate mask; eval goes straight to edges (per-pixel bbox
// test is redundant: inside => bbox containment). chdr[c] = GLOBAL suffix min
// <= split's remaining-chunk min -> break is conservative for every split.
// Winner = commutative min of (zp_bits<<32)|orig_idx; bit-exact ref math.
__global__ __launch_bounds__(256) void raster_kernel(
    const unsigned* __restrict__ chdr,
    const float* __restrict__ zbS,
    const float4* __restrict__ bbS,
    const float4* __restrict__ gmS,
    const int* __restrict__ oiS,
    unsigned long long* __restrict__ keybuf) {
  int bz = blockIdx.z;
  int b = bz >> 2, sp = bz & (NSPLIT - 1);
  int w = threadIdx.x >> 6;                // wave 0..3 -> 2x2 tile grid
  int lane = threadIdx.x & 63;
  int slot = lane & 3;
  int p = lane >> 2;                       // 0..15
  int wx = (blockIdx.x * 2 + (w & 1)) * 4;
  int wy = (blockIdx.y * 2 + (w >> 1)) * 4;
  int x = wx + (p & 3);
  int y = wy + (p >> 2);
  float px = (float)x + 0.5f, py = (float)y + 0.5f;
  float tx0 = (float)wx + 0.5f, tx1 = (float)wx + 3.5f;   // tile pixel-center rect
  float ty0 = (float)wy + 0.5f, ty1 = (float)wy + 3.5f;
  const unsigned* chdrB = chdr + b * CHDR_STRIDE;
  const float*  zbB = zbS + (size_t)b * FPAD;
  const float4* bbB = bbS + (size_t)b * FPAD;
  const float4* gmB = gmS + (size_t)b * FPAD * 4;
  const int*    oiB = oiS + (size_t)b * FPAD;

  unsigned long long bestKey = KEY_INIT;

  for (int c = sp; c < NCHUNK; c += NSPLIT) {
    float bz_ = __uint_as_float((unsigned)(bestKey >> 32));
    float comb = fminf(bz_, __shfl_xor(bz_, 1));      // min over 4 slots = pixel best
    comb = fminf(comb, __shfl_xor(comb, 2));
    float czb = __uint_as_float(chdrB[c]);            // suffix min over chunks >= c
    if (!__any(czb <= comb)) break;
    float combMax = fmaxf(comb, __shfl_xor(comb, 4)); // max over 16 pixels
    combMax = fmaxf(combMax, __shfl_xor(combMax, 8));
    combMax = fmaxf(combMax, __shfl_xor(combMax, 16));
    combMax = fmaxf(combMax, __shfl_xor(combMax, 32));
    int base = c * FCHUNK;
    #pragma unroll
    for (int h = 0; h < FCHUNK / 64; ++h) {
      int fbase = base + h * 64;
      float zb_lane = zbB[fbase + lane];              // coalesced, 1 per 64 faces
      float4 bb = bbB[fbase + lane];                  // coalesced bbox
      bool pass = (zb_lane <= combMax) &&
                  (bb.x <= tx1) && (bb.y >= tx0) &&   // bbox overlaps tile rect
                  (bb.z <= ty1) && (bb.w >= ty0);
      unsigned long long m = __ballot(pass);
      unsigned long long mm = m;
      while (mm) {
        int bit = __builtin_ctzll(mm);
        int g = bit & ~3;                             // nibble = 4-face group
        mm &= ~(0xFULL << g);
        if ((m >> (g + slot)) & 1) {
          int fi = fbase + g + slot;
          const float4* gm = &gmB[(size_t)fi * 4];
          float4 q0 = gm[0], q1 = gm[1], q2 = gm[2], q3 = gm[3];
          float w0 = __fsub_rn(__fmul_rn(q0.x, __fsub_rn(py, q0.w)),
                               __fmul_rn(q0.y, __fsub_rn(px, q0.z)));
          float w1 = __fsub_rn(__fmul_rn(q1.x, __fsub_rn(py, q1.w)),
                               __fmul_rn(q1.y, __fsub_rn(px, q1.z)));
          float w2 = __fsub_rn(__fmul_rn(q2.x, __fsub_rn(py, q2.w)),
                               __fmul_rn(q2.y, __fsub_rn(px, q2.z)));
          float b0 = __fmul_rn(w0, q3.w);
          float b1 = __fmul_rn(w1, q3.w);
          float b2 = __fmul_rn(w2, q3.w);
          if (b0 >= 0.0f && b1 >= 0.0f && b2 >= 0.0f) {
            float invz = __fadd_rn(__fadd_rn(b0 / q3.x, b1 / q3.y), b2 / q3.z);
            if (invz > EPSF) {
              float zp = 1.0f / invz;
              unsigned long long key =
                  ((unsigned long long)__float_as_uint(zp) << 32) | (unsigned)oiB[fi];
              if (key < bestKey) bestKey = key;
            }
          }
        }
      }
    }
  }

  // merge slots within each pixel quad
  unsigned long long o = shfl_xor_u64(bestKey, 1);
  if (o < bestKey) bestKey = o;
  o = shfl_xor_u64(bestKey, 2);
  if (o < bestKey) bestKey = o;
  if (slot == 0 && bestKey != KEY_INIT)
    atomicMin(&keybuf[(size_t)b * HW + (size_t)y * W_IMG + x], bestKey);
}

__global__ void shade_kernel(const unsigned long long* __restrict__ keybuf,
                             const float4* __restrict__ gmS,
                             const int* __restrict__ inv,
                             const int* __restrict__ f,
                             const float* __restrict__ vc,
                             const float* __restrict__ bg,
                             float* __restrict__ out) {
  int p = blockIdx.x * blockDim.x + threadIdx.x;
  if (p >= NB * HW) return;
  int b = p / HW, pix = p - b * HW;
  int y = pix / W_IMG, x = pix - y * W_IMG;
  float px = (float)x + 0.5f, py = (float)y + 0.5f;
  unsigned long long key = keybuf[p];
  float o0, o1, o2;
  if (key != KEY_INIT) {
    int best = (int)(unsigned)(key & 0xFFFFFFFFu);
    float zmin = __uint_as_float((unsigned)(key >> 32));
    int pos = inv[b * NF + best];
    const float4* g = &gmS[((size_t)b * FPAD + pos) * 4];
    float4 q0 = g[0], q1 = g[1], q2 = g[2], q3 = g[3];
    float w0 = __fsub_rn(__fmul_rn(q0.x, __fsub_rn(py, q0.w)),
                         __fmul_rn(q0.y, __fsub_rn(px, q0.z)));
    float w1 = __fsub_rn(__fmul_rn(q1.x, __fsub_rn(py, q1.w)),
                         __fmul_rn(q1.y, __fsub_rn(px, q1.z)));
    float w2 = __fsub_rn(__fmul_rn(q2.x, __fsub_rn(py, q2.w)),
                         __fmul_rn(q2.y, __fsub_rn(px, q2.z)));
    float b0 = __fmul_rn(w0, q3.w), b1 = __fmul_rn(w1, q3.w), b2 = __fmul_rn(w2, q3.w);
    float pc0 = b0 / q3.x, pc1 = b1 / q3.y, pc2 = b2 / q3.z;
    int i0 = f[best * 3 + 0], i1 = f[best * 3 + 1], i2 = f[best * 3 + 2];
    const float* c0p = vc + (size_t)i0 * 3;
    const float* c1p = vc + (size_t)i1 * 3;
    const float* c2p = vc + (size_t)i2 * 3;
    o0 = __fmul_rn(__fadd_rn(__fadd_rn(__fmul_rn(pc0, c0p[0]), __fmul_rn(pc1, c1p[0])),
                             __fmul_rn(pc2, c2p[0])), zmin);
    o1 = __fmul_rn(__fadd_rn(__fadd_rn(__fmul_rn(pc0, c0p[1]), __fmul_rn(pc1, c1p[1])),
                             __fmul_rn(pc2, c2p[1])), zmin);
    o2 = __fmul_rn(__fadd_rn(__fadd_rn(__fmul_rn(pc0, c0p[2]), __fmul_rn(pc1, c1p[2])),
                             __fmul_rn(pc2, c2p[2])), zmin);
  } else {
    o0 = bg[0]; o1 = bg[1]; o2 = bg[2];
  }
  size_t o = (size_t)p * 3;
  out[o + 0] = o0;
  out[o + 1] = o1;
  out[o + 2] = o2;
}

extern "C" void kernel_launch(void* const* d_in, const int* in_sizes, int n_in,
                              void* d_out, int out_size, void* d_ws, size_t ws_size,
                              hipStream_t stream) {
  const float* v   = (const float*)d_in[0];
  const float* vc  = (const float*)d_in[1];
  const float* bg  = (const float*)d_in[2];
  const float* cf  = (const float*)d_in[3];
  const float* cc  = (const float*)d_in[4];
  const float* ct  = (const float*)d_in[5];
  const float* crt = (const float*)d_in[6];
  const int*   f   = (const int*)d_in[7];
  float* out = (float*)d_out;
  char* ws = (char*)d_ws;

  float4*   verts = (float4*)(ws + OFF_VERTS);
  float*    zbU   = (float*)(ws + OFF_ZBU);
  float*    zbS   = (float*)(ws + OFF_ZBS);
  float4*   bbS   = (float4*)(ws + OFF_BBS);
  float4*   gmS   = (float4*)(ws + OFF_GMS);
  int*      oiS   = (int*)(ws + OFF_OIS);
  int*      inv   = (int*)(ws + OFF_INV);
  unsigned* chdr  = (unsigned*)(ws + OFF_CHDR);
  unsigned* cnt   = (unsigned*)(ws + OFF_CNT);
  unsigned* offs  = (unsigned*)(ws + OFF_OFFS);
  unsigned long long* keybuf = (unsigned long long*)(ws + OFF_KEY);

  hipLaunchKernelGGL(proj_init_kernel, dim3((NB * HW + 255) / 256), dim3(256), 0, stream,
                     v, cf, cc, ct, crt, verts, keybuf, zbS, bbS, chdr, cnt);
  hipLaunchKernelGGL(zb_kernel, dim3((NB * NF + 255) / 256), dim3(256), 0, stream,
                     f, verts, zbU, cnt);
  hipLaunchKernelGGL(scan_kernel, dim3(NB), dim3(1024), 0, stream, cnt, offs);
  hipLaunchKernelGGL(scatter_kernel, dim3((NB * NF + 255) / 256), dim3(256), 0, stream,
                     f, verts, zbU, offs, zbS, bbS, gmS, oiS, inv, chdr);
  hipLaunchKernelGGL(suffix_kernel, dim3(NB), dim3(CHDR_STRIDE), 0, stream, chdr);
  hipLaunchKernelGGL(raster_kernel, dim3(W_IMG / 8, H_IMG / 8, NB * NSPLIT),
                     dim3(256), 0, stream, chdr, zbS, bbS, gmS, oiS, keybuf);
  hipLaunchKernelGGL(shade_kernel, dim3((NB * HW + 255) / 256), dim3(256), 0, stream,
                     keybuf, gmS, inv, f, vc, bg, out);
}

// Round 12
// 363.413 us; speedup vs baseline: 1.0488x; 1.0488x over previous
//
#include <hip/hip_runtime.h>
#include <math.h>

#define H_IMG 224
#define W_IMG 224
#define HW (H_IMG * W_IMG)
#define EPSF 1e-8f
#define NV 6890
#define NF 13776
#define NB 2
#define FCHUNK 128
#define NCHUNK ((NF + FCHUNK - 1) / FCHUNK)   // 108
#define FPAD (NCHUNK * FCHUNK)                // 13824
#define NSPLIT 4
#define NBUCK 1024
#define CHDR_STRIDE 128
#define KEY_INIT 0x7F800000FFFFFFFFULL        // zp=+inf, idx=~0

// workspace byte offsets (256-aligned)
#define OFF_VERTS 0u                          // NB*NV*16      = 220,480
#define OFF_ZBU   220672u                     // NB*NF*4       = 110,208
#define OFF_ZBS   331008u                     // NB*FPAD*4     = 110,592
#define OFF_BBS   441600u                     // NB*FPAD*16    = 442,368
#define OFF_GMS   883968u                     // NB*FPAD*64    = 1,769,472
#define OFF_OIS   2653440u                    // NB*FPAD*4     = 110,592
#define OFF_INV   2764032u                    // NB*NF*4       = 110,208
#define OFF_CHDR  2874368u                    // NB*128*4      = 1,024
#define OFF_CNT   2875392u                    // NB*1024*4     = 8,192
#define OFF_OFFS  2883584u                    // NB*1024*4     = 8,192
#define OFF_KEY   2891776u                    // NB*HW*8       = 802,816  (end ~3.69 MB)

__device__ inline unsigned long long shfl_xor_u64(unsigned long long v, int m) {
  unsigned lo = (unsigned)v, hi = (unsigned)(v >> 32);
  lo = __shfl_xor(lo, m);
  hi = __shfl_xor(hi, m);
  return ((unsigned long long)hi << 32) | lo;
}

// Projection fused with all buffer inits (one launch, grid covers NB*HW).
__global__ void proj_init_kernel(const float* __restrict__ v,
                                 const float* __restrict__ cf,
                                 const float* __restrict__ cc,
                                 const float* __restrict__ ct,
                                 const float* __restrict__ crt,
                                 float4* __restrict__ verts,
                                 unsigned long long* __restrict__ keybuf,
                                 float* __restrict__ zbS, float4* __restrict__ bbS,
                                 unsigned* __restrict__ chdr, unsigned* __restrict__ cnt) {
  int i = blockIdx.x * blockDim.x + threadIdx.x;
  if (i < NB * NV) {
    float r0 = crt[0], r1 = crt[1], r2 = crt[2];
    float ss = __fadd_rn(__fadd_rn(__fmul_rn(r0, r0), __fmul_rn(r1, r1)), __fmul_rn(r2, r2));
    float th = sqrtf(__fadd_rn(ss, 1e-12f));
    float kx = r0 / th, ky = r1 / th, kz = r2 / th;
    float c = cosf(th), s = sinf(th), oc = 1.0f - c;
    float R00 = c + oc * kx * kx,      R01 = oc * kx * ky - s * kz, R02 = oc * kx * kz + s * ky;
    float R10 = oc * ky * kx + s * kz, R11 = c + oc * ky * ky,      R12 = oc * ky * kz - s * kx;
    float R20 = oc * kz * kx - s * ky, R21 = oc * kz * ky + s * kx, R22 = c + oc * kz * kz;
    float x = v[i * 3 + 0], y = v[i * 3 + 1], z = v[i * 3 + 2];
    float xc = R00 * x + R01 * y + R02 * z + ct[0];
    float yc = R10 * x + R11 * y + R12 * z + ct[1];
    float zc = R20 * x + R21 * y + R22 * z + ct[2];
    float zs = fmaxf(zc, EPSF);
    float u = __fadd_rn(__fmul_rn(xc / zs, cf[0]), cc[0]);
    float w = __fadd_rn(__fmul_rn(yc / zs, cf[1]), cc[1]);
    verts[i] = make_float4(u, w, zc, 0.0f);
  }
  if (i < NB * HW) keybuf[i] = KEY_INIT;
  if (i < NB * FPAD) {
    zbS[i] = 3e30f;                                      // pad: sorts last
    bbS[i] = make_float4(1e30f, -1e30f, 1e30f, -1e30f);  // always-miss -> prefilter kills
  }
  if (i < NB * CHDR_STRIDE) chdr[i] = 0x7F800000u;       // +inf bits
  if (i < NB * NBUCK) cnt[i] = 0u;
}

// Depth lower-bound per face + bucket histogram.
// zb <= zp guaranteed: zp = 1/(sum b_i/z_i) >= minz/(1+serr), serr ~ 3*werr/|area|
// with werr ~5 ulps of the largest edge-function product term. Tight bound
// (slack 1e-3) only when 3*werr <= 5e-4*|area|; else zb=0 (never depth-culled).
__global__ void zb_kernel(const int* __restrict__ f, const float4* __restrict__ verts,
                          float* __restrict__ zbU, unsigned* __restrict__ cnt) {
  int i = blockIdx.x * blockDim.x + threadIdx.x;
  if (i >= NB * NF) return;
  int b = i / NF, fi = i - b * NF;
  int i0 = f[fi * 3 + 0], i1 = f[fi * 3 + 1], i2 = f[fi * 3 + 2];
  float4 p0 = verts[b * NV + i0], p1 = verts[b * NV + i1], p2 = verts[b * NV + i2];
  float area = __fsub_rn(__fmul_rn(__fsub_rn(p1.x, p0.x), __fsub_rn(p2.y, p0.y)),
                         __fmul_rn(__fsub_rn(p1.y, p0.y), __fsub_rn(p2.x, p0.x)));
  bool nz = fabsf(area) > EPSF;
  bool zv = (p0.z > EPSF) && (p1.z > EPSF) && (p2.z > EPSF);
  bool ok = nz && zv;
  float zb;
  if (!ok) {
    zb = 3e30f;  // invalid: can never produce a hit (inv_z <= EPS); sorts last
  } else {
    float minz = fminf(fminf(fmaxf(p0.z, EPSF), fmaxf(p1.z, EPSF)), fmaxf(p2.z, EPSF));
    float M = fmaxf(fmaxf(fmaxf(fabsf(p0.x), fabsf(p0.y)), fmaxf(fabsf(p1.x), fabsf(p1.y))),
                    fmaxf(fabsf(p2.x), fabsf(p2.y)));
    float werr = (2.0f * M) * (M + 256.0f) * 6e-7f;
    bool tight = (3.0f * werr) <= (5e-4f * fabsf(area));
    zb = tight ? __fmul_rn(minz, 0.999f) : 0.0f;
  }
  zbU[i] = zb;
  int bucket = (int)fminf(fmaxf(zb * 256.0f, 0.0f), (float)(NBUCK - 1));
  atomicAdd(&cnt[b * NBUCK + bucket], 1u);
}

// Shfl-based exclusive scan over 1024 buckets (2 barriers).
__global__ __launch_bounds__(1024) void scan_kernel(const unsigned* __restrict__ cnt,
                                                    unsigned* __restrict__ offs) {
  __shared__ unsigned wsum[16];
  int t = threadIdx.x, b = blockIdx.x;
  int lane = t & 63, wid = t >> 6;
  unsigned v = cnt[b * NBUCK + t];
  unsigned acc = v;
  #pragma unroll
  for (int d = 1; d < 64; d <<= 1) {
    unsigned n = __shfl_up(acc, d);
    if (lane >= d) acc += n;
  }
  if (lane == 63) wsum[wid] = acc;
  __syncthreads();
  if (t < 16) {
    unsigned wv = wsum[t];
    #pragma unroll
    for (int d = 1; d < 16; d <<= 1) {
      unsigned n = __shfl_up(wv, d, 16);
      if (t >= d) wv += n;
    }
    wsum[t] = wv;
  }
  __syncthreads();
  unsigned base = (wid > 0) ? wsum[wid - 1] : 0u;
  offs[b * NBUCK + t] = base + acc - v;  // exclusive
}

// Scatter into depth-sorted SoA. Record values use the exact reference fp32 op
// sequence -> bit-identical results regardless of within-bucket position.
__global__ void scatter_kernel(const int* __restrict__ f, const float4* __restrict__ verts,
                               const float* __restrict__ zbU, unsigned* __restrict__ offs,
                               float* __restrict__ zbS, float4* __restrict__ bbS,
                               float4* __restrict__ gmS, int* __restrict__ oiS,
                               int* __restrict__ inv, unsigned* __restrict__ chdr) {
  int i = blockIdx.x * blockDim.x + threadIdx.x;
  if (i >= NB * NF) return;
  int b = i / NF, fi = i - b * NF;
  float zb = zbU[i];
  int bucket = (int)fminf(fmaxf(zb * 256.0f, 0.0f), (float)(NBUCK - 1));
  unsigned pos = atomicAdd(&offs[b * NBUCK + bucket], 1u);
  int i0 = f[fi * 3 + 0], i1 = f[fi * 3 + 1], i2 = f[fi * 3 + 2];
  float4 p0 = verts[b * NV + i0], p1 = verts[b * NV + i1], p2 = verts[b * NV + i2];
  float x0 = p0.x, y0 = p0.y, z0 = p0.z;
  float x1 = p1.x, y1 = p1.y, z1 = p1.z;
  float x2 = p2.x, y2 = p2.y, z2 = p2.z;
  float area = __fsub_rn(__fmul_rn(__fsub_rn(x1, x0), __fsub_rn(y2, y0)),
                         __fmul_rn(__fsub_rn(y1, y0), __fsub_rn(x2, x0)));
  bool nz = fabsf(area) > EPSF;
  float inv_area = nz ? (1.0f / area) : 0.0f;
  bool zv = (z0 > EPSF) && (z1 > EPSF) && (z2 > EPSF);
  bool ok = nz && zv;
  float zz0 = ok ? fmaxf(z0, EPSF) : 1e30f;
  float zz1 = ok ? fmaxf(z1, EPSF) : 1e30f;
  float zz2 = ok ? fmaxf(z2, EPSF) : 1e30f;
  size_t sp_ = (size_t)b * FPAD + pos;
  zbS[sp_] = zb;
  bbS[sp_] = make_float4(fminf(fminf(x0, x1), x2), fmaxf(fmaxf(x0, x1), x2),
                         fminf(fminf(y0, y1), y2), fmaxf(fmaxf(y0, y1), y2));
  gmS[sp_ * 4 + 0] = make_float4(__fsub_rn(x2, x1), __fsub_rn(y2, y1), x1, y1);
  gmS[sp_ * 4 + 1] = make_float4(__fsub_rn(x0, x2), __fsub_rn(y0, y2), x2, y2);
  gmS[sp_ * 4 + 2] = make_float4(__fsub_rn(x1, x0), __fsub_rn(y1, y0), x0, y0);
  gmS[sp_ * 4 + 3] = make_float4(zz0, zz1, zz2, inv_area);
  oiS[sp_] = fi;
  inv[i] = (int)pos;
  atomicMin(&chdr[b * CHDR_STRIDE + (int)(pos / FCHUNK)], __float_as_uint(zb));
}

// Suffix-min over chunk headers: chdr[c] := min over chunks >= c (uint min is
// order-preserving for nonnegative floats) -> raster break is conservative.
__global__ __launch_bounds__(CHDR_STRIDE) void suffix_kernel(unsigned* __restrict__ chdr) {
  __shared__ unsigned s[CHDR_STRIDE];
  int t = threadIdx.x, b = blockIdx.x;
  s[t] = chdr[b * CHDR_STRIDE + t];
  __syncthreads();
  for (int d = 1; d < CHDR_STRIDE; d <<= 1) {
    unsigned v = (t + d < CHDR_STRIDE) ? s[t + d] : 0x7F800000u;
    __syncthreads();
    s[t] = (v < s[t]) ? v : s[t];
    __syncthreads();
  }
  chdr[b * CHDR_STRIDE + t] = s[t];
}

// Block = 256 threads = 4 independent waves; each wave owns a 4x4 pixel tile
// (16 pixels x 4 face-slots). NSPLIT=4 blocks per tile scan interleaved chunk
// subsequences and merge via keybuf atomicMin (load balance). NEW: once per
// chunk each pixel folds in a plain load of keybuf[pixel] — the globally
// merged best — re-coupling the splits' convergence (R11's regression was
// per-split bounds staying ~4x looser). Stale reads are conservative (larger
// key -> looser bound -> extra evals, never missed winners). Prefilter per
// 64-face half-chunk: lane loads zb AND bbox (coalesced); pass = depth &&
// bbox-overlaps-tile; one __ballot -> mask; eval goes straight to edges.
// chdr[c] = global suffix min -> break conservative for every split.
// Winner = commutative min of (zp_bits<<32)|orig_idx; bit-exact ref math.
__global__ __launch_bounds__(256) void raster_kernel(
    const unsigned* __restrict__ chdr,
    const float* __restrict__ zbS,
    const float4* __restrict__ bbS,
    const float4* __restrict__ gmS,
    const int* __restrict__ oiS,
    unsigned long long* __restrict__ keybuf) {
  int bz = blockIdx.z;
  int b = bz >> 2, sp = bz & (NSPLIT - 1);
  int w = threadIdx.x >> 6;                // wave 0..3 -> 2x2 tile grid
  int lane = threadIdx.x & 63;
  int slot = lane & 3;
  int p = lane >> 2;                       // 0..15
  int wx = (blockIdx.x * 2 + (w & 1)) * 4;
  int wy = (blockIdx.y * 2 + (w >> 1)) * 4;
  int x = wx + (p & 3);
  int y = wy + (p >> 2);
  float px = (float)x + 0.5f, py = (float)y + 0.5f;
  float tx0 = (float)wx + 0.5f, tx1 = (float)wx + 3.5f;   // tile pixel-center rect
  float ty0 = (float)wy + 0.5f, ty1 = (float)wy + 3.5f;
  const unsigned* chdrB = chdr + b * CHDR_STRIDE;
  const float*  zbB = zbS + (size_t)b * FPAD;
  const float4* bbB = bbS + (size_t)b * FPAD;
  const float4* gmB = gmS + (size_t)b * FPAD * 4;
  const int*    oiB = oiS + (size_t)b * FPAD;
  size_t kidx = (size_t)b * HW + (size_t)y * W_IMG + x;

  unsigned long long bestKey = KEY_INIT;
  unsigned long long lastSeen = KEY_INIT;  // last keybuf value folded in

  for (int c = sp; c < NCHUNK; c += NSPLIT) {
    // fold in the cross-split merged best (plain load; stale = conservative)
    unsigned long long gk = keybuf[kidx];
    if (gk < bestKey) bestKey = gk;
    if (gk < lastSeen) lastSeen = gk;
    float bz_ = __uint_as_float((unsigned)(bestKey >> 32));
    float comb = fminf(bz_, __shfl_xor(bz_, 1));      // min over 4 slots = pixel best
    comb = fminf(comb, __shfl_xor(comb, 2));
    float czb = __uint_as_float(chdrB[c]);            // suffix min over chunks >= c
    if (!__any(czb <= comb)) break;
    float combMax = fmaxf(comb, __shfl_xor(comb, 4)); // max over 16 pixels
    combMax = fmaxf(combMax, __shfl_xor(combMax, 8));
    combMax = fmaxf(combMax, __shfl_xor(combMax, 16));
    combMax = fmaxf(combMax, __shfl_xor(combMax, 32));
    int base = c * FCHUNK;
    #pragma unroll
    for (int h = 0; h < FCHUNK / 64; ++h) {
      int fbase = base + h * 64;
      float zb_lane = zbB[fbase + lane];              // coalesced, 1 per 64 faces
      float4 bb = bbB[fbase + lane];                  // coalesced bbox
      bool pass = (zb_lane <= combMax) &&
                  (bb.x <= tx1) && (bb.y >= tx0) &&   // bbox overlaps tile rect
                  (bb.z <= ty1) && (bb.w >= ty0);
      unsigned long long m = __ballot(pass);
      unsigned long long mm = m;
      while (mm) {
        int bit = __builtin_ctzll(mm);
        int g = bit & ~3;                             // nibble = 4-face group
        mm &= ~(0xFULL << g);
        if ((m >> (g + slot)) & 1) {
          int fi = fbase + g + slot;
          const float4* gm = &gmB[(size_t)fi * 4];
          float4 q0 = gm[0], q1 = gm[1], q2 = gm[2], q3 = gm[3];
          float w0 = __fsub_rn(__fmul_rn(q0.x, __fsub_rn(py, q0.w)),
                               __fmul_rn(q0.y, __fsub_rn(px, q0.z)));
          float w1 = __fsub_rn(__fmul_rn(q1.x, __fsub_rn(py, q1.w)),
                               __fmul_rn(q1.y, __fsub_rn(px, q1.z)));
          float w2 = __fsub_rn(__fmul_rn(q2.x, __fsub_rn(py, q2.w)),
                               __fmul_rn(q2.y, __fsub_rn(px, q2.z)));
          float b0 = __fmul_rn(w0, q3.w);
          float b1 = __fmul_rn(w1, q3.w);
          float b2 = __fmul_rn(w2, q3.w);
          if (b0 >= 0.0f && b1 >= 0.0f && b2 >= 0.0f) {
            float invz = __fadd_rn(__fadd_rn(b0 / q3.x, b1 / q3.y), b2 / q3.z);
            if (invz > EPSF) {
              float zp = 1.0f / invz;
              unsigned long long key =
                  ((unsigned long long)__float_as_uint(zp) << 32) | (unsigned)oiB[fi];
              if (key < bestKey) bestKey = key;
            }
          }
        }
      }
    }
  }

  // merge slots within each pixel quad
  unsigned long long o = shfl_xor_u64(bestKey, 1);
  if (o < bestKey) bestKey = o;
  o = shfl_xor_u64(bestKey, 2);
  if (o < bestKey) bestKey = o;
  // only the slot-0 lane writes, and only if we found something better than
  // the last globally-merged value we observed (suppresses redundant atomics)
  if (slot == 0 && bestKey < lastSeen)
    atomicMin(&keybuf[kidx], bestKey);
}

__global__ void shade_kernel(const unsigned long long* __restrict__ keybuf,
                             const float4* __restrict__ gmS,
                             const int* __restrict__ inv,
                             const int* __restrict__ f,
                             const float* __restrict__ vc,
                             const float* __restrict__ bg,
                             float* __restrict__ out) {
  int p = blockIdx.x * blockDim.x + threadIdx.x;
  if (p >= NB * HW) return;
  int b = p / HW, pix = p - b * HW;
  int y = pix / W_IMG, x = pix - y * W_IMG;
  float px = (float)x + 0.5f, py = (float)y + 0.5f;
  unsigned long long key = keybuf[p];
  float o0, o1, o2;
  if (key != KEY_INIT) {
    int best = (int)(unsigned)(key & 0xFFFFFFFFu);
    float zmin = __uint_as_float((unsigned)(key >> 32));
    int pos = inv[b * NF + best];
    const float4* g = &gmS[((size_t)b * FPAD + pos) * 4];
    float4 q0 = g[0], q1 = g[1], q2 = g[2], q3 = g[3];
    float w0 = __fsub_rn(__fmul_rn(q0.x, __fsub_rn(py, q0.w)),
                         __fmul_rn(q0.y, __fsub_rn(px, q0.z)));
    float w1 = __fsub_rn(__fmul_rn(q1.x, __fsub_rn(py, q1.w)),
                         __fmul_rn(q1.y, __fsub_rn(px, q1.z)));
    float w2 = __fsub_rn(__fmul_rn(q2.x, __fsub_rn(py, q2.w)),
                         __fmul_rn(q2.y, __fsub_rn(px, q2.z)));
    float b0 = __fmul_rn(w0, q3.w), b1 = __fmul_rn(w1, q3.w), b2 = __fmul_rn(w2, q3.w);
    float pc0 = b0 / q3.x, pc1 = b1 / q3.y, pc2 = b2 / q3.z;
    int i0 = f[best * 3 + 0], i1 = f[best * 3 + 1], i2 = f[best * 3 + 2];
    const float* c0p = vc + (size_t)i0 * 3;
    const float* c1p = vc + (size_t)i1 * 3;
    const float* c2p = vc + (size_t)i2 * 3;
    o0 = __fmul_rn(__fadd_rn(__fadd_rn(__fmul_rn(pc0, c0p[0]), __fmul_rn(pc1, c1p[0])),
                             __fmul_rn(pc2, c0p == c1p ? 0.f : c2p[0])), zmin);
    // (dummy ternary removed below — keep exact form)
    o0 = __fmul_rn(__fadd_rn(__fadd_rn(__fmul_rn(pc0, c0p[0]), __fmul_rn(pc1, c1p[0])),
                             __fmul_rn(pc2, c2p[0])), zmin);
    o1 = __fmul_rn(__fadd_rn(__fadd_rn(__fmul_rn(pc0, c0p[1]), __fmul_rn(pc1, c1p[1])),
                             __fmul_rn(pc2, c2p[1])), zmin);
    o2 = __fmul_rn(__fadd_rn(__fadd_rn(__fmul_rn(pc0, c0p[2]), __fmul_rn(pc1, c1p[2])),
                             __fmul_rn(pc2, c2p[2])), zmin);
  } else {
    o0 = bg[0]; o1 = bg[1]; o2 = bg[2];
  }
  size_t o = (size_t)p * 3;
  out[o + 0] = o0;
  out[o + 1] = o1;
  out[o + 2] = o2;
}

extern "C" void kernel_launch(void* const* d_in, const int* in_sizes, int n_in,
                              void* d_out, int out_size, void* d_ws, size_t ws_size,
                              hipStream_t stream) {
  const float* v   = (const float*)d_in[0];
  const float* vc  = (const float*)d_in[1];
  const float* bg  = (const float*)d_in[2];
  const float* cf  = (const float*)d_in[3];
  const float* cc  = (const float*)d_in[4];
  const float* ct  = (const float*)d_in[5];
  const float* crt = (const float*)d_in[6];
  const int*   f   = (const int*)d_in[7];
  float* out = (float*)d_out;
  char* ws = (char*)d_ws;

  float4*   verts = (float4*)(ws + OFF_VERTS);
  float*    zbU   = (float*)(ws + OFF_ZBU);
  float*    zbS   = (float*)(ws + OFF_ZBS);
  float4*   bbS   = (float4*)(ws + OFF_BBS);
  float4*   gmS   = (float4*)(ws + OFF_GMS);
  int*      oiS   = (int*)(ws + OFF_OIS);
  int*      inv   = (int*)(ws + OFF_INV);
  unsigned* chdr  = (unsigned*)(ws + OFF_CHDR);
  unsigned* cnt   = (unsigned*)(ws + OFF_CNT);
  unsigned* offs  = (unsigned*)(ws + OFF_OFFS);
  unsigned long long* keybuf = (unsigned long long*)(ws + OFF_KEY);

  hipLaunchKernelGGL(proj_init_kernel, dim3((NB * HW + 255) / 256), dim3(256), 0, stream,
                     v, cf, cc, ct, crt, verts, keybuf, zbS, bbS, chdr, cnt);
  hipLaunchKernelGGL(zb_kernel, dim3((NB * NF + 255) / 256), dim3(256), 0, stream,
                     f, verts, zbU, cnt);
  hipLaunchKernelGGL(scan_kernel, dim3(NB), dim3(1024), 0, stream, cnt, offs);
  hipLaunchKernelGGL(scatter_kernel, dim3((NB * NF + 255) / 256), dim3(256), 0, stream,
                     f, verts, zbU, offs, zbS, bbS, gmS, oiS, inv, chdr);
  hipLaunchKernelGGL(suffix_kernel, dim3(NB), dim3(CHDR_STRIDE), 0, stream, chdr);
  hipLaunchKernelGGL(raster_kernel, dim3(W_IMG / 8, H_IMG / 8, NB * NSPLIT),
                     dim3(256), 0, stream, chdr, zbS, bbS, gmS, oiS, keybuf);
  hipLaunchKernelGGL(shade_kernel, dim3((NB * HW + 255) / 256), dim3(256), 0, stream,
                     keybuf, gmS, inv, f, vc, bg, out);
}

// Round 13
// 302.057 us; speedup vs baseline: 1.2619x; 1.2031x over previous
//
#include <hip/hip_runtime.h>
#include <math.h>

#define H_IMG 224
#define W_IMG 224
#define HW (H_IMG * W_IMG)
#define EPSF 1e-8f
#define NV 6890
#define NF 13776
#define NB 2
#define FCHUNK 128
#define NCHUNK ((NF + FCHUNK - 1) / FCHUNK)   // 108
#define FPAD (NCHUNK * FCHUNK)                // 13824
#define NBUCK 1024
#define CHDR_STRIDE 128
#define KEY_INIT 0x7F800000FFFFFFFFULL        // zp=+inf, idx=~0

// workspace byte offsets (256-aligned)
#define OFF_VERTS 0u                          // NB*NV*16      = 220,480
#define OFF_ZBU   220672u                     // NB*NF*4       = 110,208
#define OFF_ZBS   331008u                     // NB*FPAD*4     = 110,592
#define OFF_BBS   441600u                     // NB*FPAD*16    = 442,368
#define OFF_GMS   883968u                     // NB*FPAD*64    = 1,769,472
#define OFF_OIS   2653440u                    // NB*FPAD*4     = 110,592
#define OFF_INV   2764032u                    // NB*NF*4       = 110,208
#define OFF_CHDR  2874368u                    // NB*128*4      = 1,024
#define OFF_CNT   2875392u                    // NB*1024*4     = 8,192
#define OFF_OFFS  2883584u                    // NB*1024*4     = 8,192

__device__ inline unsigned long long shfl_xor_u64(unsigned long long v, int m) {
  unsigned lo = (unsigned)v, hi = (unsigned)(v >> 32);
  lo = __shfl_xor(lo, m);
  hi = __shfl_xor(hi, m);
  return ((unsigned long long)hi << 32) | lo;
}

// Projection fused with buffer inits (one launch, grid covers NB*HW).
__global__ void proj_init_kernel(const float* __restrict__ v,
                                 const float* __restrict__ cf,
                                 const float* __restrict__ cc,
                                 const float* __restrict__ ct,
                                 const float* __restrict__ crt,
                                 float4* __restrict__ verts,
                                 float* __restrict__ zbS, float4* __restrict__ bbS,
                                 unsigned* __restrict__ chdr, unsigned* __restrict__ cnt) {
  int i = blockIdx.x * blockDim.x + threadIdx.x;
  if (i < NB * NV) {
    float r0 = crt[0], r1 = crt[1], r2 = crt[2];
    float ss = __fadd_rn(__fadd_rn(__fmul_rn(r0, r0), __fmul_rn(r1, r1)), __fmul_rn(r2, r2));
    float th = sqrtf(__fadd_rn(ss, 1e-12f));
    float kx = r0 / th, ky = r1 / th, kz = r2 / th;
    float c = cosf(th), s = sinf(th), oc = 1.0f - c;
    float R00 = c + oc * kx * kx,      R01 = oc * kx * ky - s * kz, R02 = oc * kx * kz + s * ky;
    float R10 = oc * ky * kx + s * kz, R11 = c + oc * ky * ky,      R12 = oc * ky * kz - s * kx;
    float R20 = oc * kz * kx - s * ky, R21 = oc * kz * ky + s * kx, R22 = c + oc * kz * kz;
    float x = v[i * 3 + 0], y = v[i * 3 + 1], z = v[i * 3 + 2];
    float xc = R00 * x + R01 * y + R02 * z + ct[0];
    float yc = R10 * x + R11 * y + R12 * z + ct[1];
    float zc = R20 * x + R21 * y + R22 * z + ct[2];
    float zs = fmaxf(zc, EPSF);
    float u = __fadd_rn(__fmul_rn(xc / zs, cf[0]), cc[0]);
    float w = __fadd_rn(__fmul_rn(yc / zs, cf[1]), cc[1]);
    verts[i] = make_float4(u, w, zc, 0.0f);
  }
  if (i < NB * FPAD) {
    zbS[i] = 3e30f;                                      // pad: sorts last
    bbS[i] = make_float4(1e30f, -1e30f, 1e30f, -1e30f);  // always-miss -> prefilter kills
  }
  if (i < NB * CHDR_STRIDE) chdr[i] = 0x7F800000u;       // +inf bits
  if (i < NB * NBUCK) cnt[i] = 0u;
}

// Depth lower-bound per face + bucket histogram.
// zb <= zp guaranteed: zp = 1/(sum b_i/z_i) >= minz/(1+serr), serr ~ 3*werr/|area|
// with werr ~5 ulps of the largest edge-function product term. Tight bound
// (slack 1e-3) only when 3*werr <= 5e-4*|area|; else zb=0 (never depth-culled).
__global__ void zb_kernel(const int* __restrict__ f, const float4* __restrict__ verts,
                          float* __restrict__ zbU, unsigned* __restrict__ cnt) {
  int i = blockIdx.x * blockDim.x + threadIdx.x;
  if (i >= NB * NF) return;
  int b = i / NF, fi = i - b * NF;
  int i0 = f[fi * 3 + 0], i1 = f[fi * 3 + 1], i2 = f[fi * 3 + 2];
  float4 p0 = verts[b * NV + i0], p1 = verts[b * NV + i1], p2 = verts[b * NV + i2];
  float area = __fsub_rn(__fmul_rn(__fsub_rn(p1.x, p0.x), __fsub_rn(p2.y, p0.y)),
                         __fmul_rn(__fsub_rn(p1.y, p0.y), __fsub_rn(p2.x, p0.x)));
  bool nz = fabsf(area) > EPSF;
  bool zv = (p0.z > EPSF) && (p1.z > EPSF) && (p2.z > EPSF);
  bool ok = nz && zv;
  float zb;
  if (!ok) {
    zb = 3e30f;  // invalid: can never produce a hit (inv_z <= EPS); sorts last
  } else {
    float minz = fminf(fminf(fmaxf(p0.z, EPSF), fmaxf(p1.z, EPSF)), fmaxf(p2.z, EPSF));
    float M = fmaxf(fmaxf(fmaxf(fabsf(p0.x), fabsf(p0.y)), fmaxf(fabsf(p1.x), fabsf(p1.y))),
                    fmaxf(fabsf(p2.x), fabsf(p2.y)));
    float werr = (2.0f * M) * (M + 256.0f) * 6e-7f;
    bool tight = (3.0f * werr) <= (5e-4f * fabsf(area));
    zb = tight ? __fmul_rn(minz, 0.999f) : 0.0f;
  }
  zbU[i] = zb;
  int bucket = (int)fminf(fmaxf(zb * 256.0f, 0.0f), (float)(NBUCK - 1));
  atomicAdd(&cnt[b * NBUCK + bucket], 1u);
}

// Shfl-based exclusive scan over 1024 buckets (2 barriers).
__global__ __launch_bounds__(1024) void scan_kernel(const unsigned* __restrict__ cnt,
                                                    unsigned* __restrict__ offs) {
  __shared__ unsigned wsum[16];
  int t = threadIdx.x, b = blockIdx.x;
  int lane = t & 63, wid = t >> 6;
  unsigned v = cnt[b * NBUCK + t];
  unsigned acc = v;
  #pragma unroll
  for (int d = 1; d < 64; d <<= 1) {
    unsigned n = __shfl_up(acc, d);
    if (lane >= d) acc += n;
  }
  if (lane == 63) wsum[wid] = acc;
  __syncthreads();
  if (t < 16) {
    unsigned wv = wsum[t];
    #pragma unroll
    for (int d = 1; d < 16; d <<= 1) {
      unsigned n = __shfl_up(wv, d, 16);
      if (t >= d) wv += n;
    }
    wsum[t] = wv;
  }
  __syncthreads();
  unsigned base = (wid > 0) ? wsum[wid - 1] : 0u;
  offs[b * NBUCK + t] = base + acc - v;  // exclusive
}

// Scatter into depth-sorted SoA. Record values use the exact reference fp32 op
// sequence -> bit-identical results regardless of within-bucket position.
__global__ void scatter_kernel(const int* __restrict__ f, const float4* __restrict__ verts,
                               const float* __restrict__ zbU, unsigned* __restrict__ offs,
                               float* __restrict__ zbS, float4* __restrict__ bbS,
                               float4* __restrict__ gmS, int* __restrict__ oiS,
                               int* __restrict__ inv, unsigned* __restrict__ chdr) {
  int i = blockIdx.x * blockDim.x + threadIdx.x;
  if (i >= NB * NF) return;
  int b = i / NF, fi = i - b * NF;
  float zb = zbU[i];
  int bucket = (int)fminf(fmaxf(zb * 256.0f, 0.0f), (float)(NBUCK - 1));
  unsigned pos = atomicAdd(&offs[b * NBUCK + bucket], 1u);
  int i0 = f[fi * 3 + 0], i1 = f[fi * 3 + 1], i2 = f[fi * 3 + 2];
  float4 p0 = verts[b * NV + i0], p1 = verts[b * NV + i1], p2 = verts[b * NV + i2];
  float x0 = p0.x, y0 = p0.y, z0 = p0.z;
  float x1 = p1.x, y1 = p1.y, z1 = p1.z;
  float x2 = p2.x, y2 = p2.y, z2 = p2.z;
  float area = __fsub_rn(__fmul_rn(__fsub_rn(x1, x0), __fsub_rn(y2, y0)),
                         __fmul_rn(__fsub_rn(y1, y0), __fsub_rn(x2, x0)));
  bool nz = fabsf(area) > EPSF;
  float inv_area = nz ? (1.0f / area) : 0.0f;
  bool zv = (z0 > EPSF) && (z1 > EPSF) && (z2 > EPSF);
  bool ok = nz && zv;
  float zz0 = ok ? fmaxf(z0, EPSF) : 1e30f;
  float zz1 = ok ? fmaxf(z1, EPSF) : 1e30f;
  float zz2 = ok ? fmaxf(z2, EPSF) : 1e30f;
  size_t sp_ = (size_t)b * FPAD + pos;
  zbS[sp_] = zb;
  bbS[sp_] = make_float4(fminf(fminf(x0, x1), x2), fmaxf(fmaxf(x0, x1), x2),
                         fminf(fminf(y0, y1), y2), fmaxf(fmaxf(y0, y1), y2));
  gmS[sp_ * 4 + 0] = make_float4(__fsub_rn(x2, x1), __fsub_rn(y2, y1), x1, y1);
  gmS[sp_ * 4 + 1] = make_float4(__fsub_rn(x0, x2), __fsub_rn(y0, y2), x2, y2);
  gmS[sp_ * 4 + 2] = make_float4(__fsub_rn(x1, x0), __fsub_rn(y1, y0), x0, y0);
  gmS[sp_ * 4 + 3] = make_float4(zz0, zz1, zz2, inv_area);
  oiS[sp_] = fi;
  inv[i] = (int)pos;
  atomicMin(&chdr[b * CHDR_STRIDE + (int)(pos / FCHUNK)], __float_as_uint(zb));
}

// Suffix-min over chunk headers: chdr[c] := min over chunks >= c (uint min is
// order-preserving for nonnegative floats) -> raster break is conservative.
__global__ __launch_bounds__(CHDR_STRIDE) void suffix_kernel(unsigned* __restrict__ chdr) {
  __shared__ unsigned s[CHDR_STRIDE];
  int t = threadIdx.x, b = blockIdx.x;
  s[t] = chdr[b * CHDR_STRIDE + t];
  __syncthreads();
  for (int d = 1; d < CHDR_STRIDE; d <<= 1) {
    unsigned v = (t + d < CHDR_STRIDE) ? s[t + d] : 0x7F800000u;
    __syncthreads();
    s[t] = (v < s[t]) ? v : s[t];
    __syncthreads();
  }
  chdr[b * CHDR_STRIDE + t] = s[t];
}

// Block = 4 waves, ALL on the same 4x4 pixel tile; chunk-space split 4-way
// interleaved (c = waveId; c += 4). Cross-wave bound sharing via LDS (CU-
// coherent, no XCD staleness — R12's keybuf feedback never closed across
// XCDs): each wave publishes its per-pixel best ZP as a u32 hint (u32 writes
// can't tear; torn u64 could under-estimate the bound), reads the 4-wave min
// each chunk. Exact winner stays in registers: per-lane 64-bit packed key,
// slot-merged via shfl, published to fin[][] post-loop, min-reduced after
// __syncthreads. One block per tile -> no global atomics, no keybuf; shade
// fused into the epilogue. Skips strictly conservative (stale hint = looser);
// winner = exact min of (zp_bits<<32)|orig_idx; bit-exact ref math.
__global__ __launch_bounds__(256) void raster_kernel(
    const unsigned* __restrict__ chdr,
    const float* __restrict__ zbS,
    const float4* __restrict__ bbS,
    const float4* __restrict__ gmS,
    const int* __restrict__ oiS,
    const int* __restrict__ inv,
    const int* __restrict__ f,
    const float* __restrict__ vc,
    const float* __restrict__ bg,
    float* __restrict__ out) {
  __shared__ unsigned hint[4][16];            // [wave][pixel] zp bits
  __shared__ unsigned long long fin[4][16];   // [wave][pixel] final keys
  int b = blockIdx.z;
  int w = threadIdx.x >> 6;
  int lane = threadIdx.x & 63;
  int slot = lane & 3;
  int p = lane >> 2;                          // 0..15
  int wx = blockIdx.x * 4, wy = blockIdx.y * 4;
  int x = wx + (p & 3), y = wy + (p >> 2);
  float px = (float)x + 0.5f, py = (float)y + 0.5f;
  float tx0 = (float)wx + 0.5f, tx1 = (float)wx + 3.5f;
  float ty0 = (float)wy + 0.5f, ty1 = (float)wy + 3.5f;
  const unsigned* chdrB = chdr + b * CHDR_STRIDE;
  const float*  zbB = zbS + (size_t)b * FPAD;
  const float4* bbB = bbS + (size_t)b * FPAD;
  const float4* gmB = gmS + (size_t)b * FPAD * 4;
  const int*    oiB = oiS + (size_t)b * FPAD;

  if (threadIdx.x < 64) hint[threadIdx.x >> 4][threadIdx.x & 15] = 0x7F800000u;
  __syncthreads();

  unsigned long long bestKey = KEY_INIT;

  for (int c = w; c < NCHUNK; c += 4) {
    // publish own per-pixel zp (slot-merged, single writer per [w][p])
    unsigned z_ = (unsigned)(bestKey >> 32);
    unsigned zo = __shfl_xor(z_, 1); if (zo < z_) z_ = zo;
    zo = __shfl_xor(z_, 2); if (zo < z_) z_ = zo;
    if (slot == 0) hint[w][p] = z_;
    // read all 4 waves' hints (coherent within CU; stale = conservative)
    unsigned bzp = hint[0][p];
    unsigned h1 = hint[1][p]; if (h1 < bzp) bzp = h1;
    unsigned h2 = hint[2][p]; if (h2 < bzp) bzp = h2;
    unsigned h3 = hint[3][p]; if (h3 < bzp) bzp = h3;
    float comb = __uint_as_float(bzp);                // pixel bound (all slots same)
    float czb = __uint_as_float(chdrB[c]);            // suffix min over chunks >= c
    if (!__any(czb <= comb)) break;
    float combMax = fmaxf(comb, __shfl_xor(comb, 4)); // max over 16 pixels
    combMax = fmaxf(combMax, __shfl_xor(combMax, 8));
    combMax = fmaxf(combMax, __shfl_xor(combMax, 16));
    combMax = fmaxf(combMax, __shfl_xor(combMax, 32));
    int base = c * FCHUNK;
    #pragma unroll
    for (int h = 0; h < FCHUNK / 64; ++h) {
      int fbase = base + h * 64;
      float zb_lane = zbB[fbase + lane];              // coalesced, 1 per 64 faces
      float4 bb = bbB[fbase + lane];                  // coalesced bbox
      bool pass = (zb_lane <= combMax) &&
                  (bb.x <= tx1) && (bb.y >= tx0) &&   // bbox overlaps tile rect
                  (bb.z <= ty1) && (bb.w >= ty0);
      unsigned long long m = __ballot(pass);
      unsigned long long mm = m;
      while (mm) {
        int bit = __builtin_ctzll(mm);
        int g = bit & ~3;                             // nibble = 4-face group
        mm &= ~(0xFULL << g);
        if ((m >> (g + slot)) & 1) {
          int fi = fbase + g + slot;
          const float4* gm = &gmB[(size_t)fi * 4];
          float4 q0 = gm[0], q1 = gm[1], q2 = gm[2], q3 = gm[3];
          float w0 = __fsub_rn(__fmul_rn(q0.x, __fsub_rn(py, q0.w)),
                               __fmul_rn(q0.y, __fsub_rn(px, q0.z)));
          float w1 = __fsub_rn(__fmul_rn(q1.x, __fsub_rn(py, q1.w)),
                               __fmul_rn(q1.y, __fsub_rn(px, q1.z)));
          float w2 = __fsub_rn(__fmul_rn(q2.x, __fsub_rn(py, q2.w)),
                               __fmul_rn(q2.y, __fsub_rn(px, q2.z)));
          float b0 = __fmul_rn(w0, q3.w);
          float b1 = __fmul_rn(w1, q3.w);
          float b2 = __fmul_rn(w2, q3.w);
          if (b0 >= 0.0f && b1 >= 0.0f && b2 >= 0.0f) {
            float invz = __fadd_rn(__fadd_rn(b0 / q3.x, b1 / q3.y), b2 / q3.z);
            if (invz > EPSF) {
              float zp = 1.0f / invz;
              unsigned long long key =
                  ((unsigned long long)__float_as_uint(zp) << 32) | (unsigned)oiB[fi];
              if (key < bestKey) bestKey = key;
            }
          }
        }
      }
    }
  }

  // exact per-wave per-pixel merge (slots), publish, then block-wide merge
  unsigned long long o = shfl_xor_u64(bestKey, 1);
  if (o < bestKey) bestKey = o;
  o = shfl_xor_u64(bestKey, 2);
  if (o < bestKey) bestKey = o;
  if (slot == 0) fin[w][p] = bestKey;
  __syncthreads();

  int t = threadIdx.x;
  if (t < 16) {
    unsigned long long key = fin[0][t];
    unsigned long long k1 = fin[1][t]; if (k1 < key) key = k1;
    unsigned long long k2 = fin[2][t]; if (k2 < key) key = k2;
    unsigned long long k3 = fin[3][t]; if (k3 < key) key = k3;
    int xx = wx + (t & 3), yy = wy + (t >> 2);
    float pxx = (float)xx + 0.5f, pyy = (float)yy + 0.5f;
    float o0, o1, o2;
    if (key != KEY_INIT) {
      int best = (int)(unsigned)(key & 0xFFFFFFFFu);
      float zmin = __uint_as_float((unsigned)(key >> 32));
      int pos = inv[b * NF + best];
      const float4* g = &gmB[(size_t)pos * 4];
      float4 q0 = g[0], q1 = g[1], q2 = g[2], q3 = g[3];
      float w0 = __fsub_rn(__fmul_rn(q0.x, __fsub_rn(pyy, q0.w)),
                           __fmul_rn(q0.y, __fsub_rn(pxx, q0.z)));
      float w1 = __fsub_rn(__fmul_rn(q1.x, __fsub_rn(pyy, q1.w)),
                           __fmul_rn(q1.y, __fsub_rn(pxx, q1.z)));
      float w2 = __fsub_rn(__fmul_rn(q2.x, __fsub_rn(pyy, q2.w)),
                           __fmul_rn(q2.y, __fsub_rn(pxx, q2.z)));
      float b0 = __fmul_rn(w0, q3.w), b1 = __fmul_rn(w1, q3.w), b2 = __fmul_rn(w2, q3.w);
      float pc0 = b0 / q3.x, pc1 = b1 / q3.y, pc2 = b2 / q3.z;
      int i0 = f[best * 3 + 0], i1 = f[best * 3 + 1], i2 = f[best * 3 + 2];
      const float* c0p = vc + (size_t)i0 * 3;
      const float* c1p = vc + (size_t)i1 * 3;
      const float* c2p = vc + (size_t)i2 * 3;
      o0 = __fmul_rn(__fadd_rn(__fadd_rn(__fmul_rn(pc0, c0p[0]), __fmul_rn(pc1, c1p[0])),
                               __fmul_rn(pc2, c2p[0])), zmin);
      o1 = __fmul_rn(__fadd_rn(__fadd_rn(__fmul_rn(pc0, c0p[1]), __fmul_rn(pc1, c1p[1])),
                               __fmul_rn(pc2, c2p[1])), zmin);
      o2 = __fmul_rn(__fadd_rn(__fadd_rn(__fmul_rn(pc0, c0p[2]), __fmul_rn(pc1, c1p[2])),
                               __fmul_rn(pc2, c2p[2])), zmin);
    } else {
      o0 = bg[0]; o1 = bg[1]; o2 = bg[2];
    }
    size_t oo = ((size_t)(b * H_IMG + yy) * W_IMG + xx) * 3;
    out[oo + 0] = o0;
    out[oo + 1] = o1;
    out[oo + 2] = o2;
  }
}

extern "C" void kernel_launch(void* const* d_in, const int* in_sizes, int n_in,
                              void* d_out, int out_size, void* d_ws, size_t ws_size,
                              hipStream_t stream) {
  const float* v   = (const float*)d_in[0];
  const float* vc  = (const float*)d_in[1];
  const float* bg  = (const float*)d_in[2];
  const float* cf  = (const float*)d_in[3];
  const float* cc  = (const float*)d_in[4];
  const float* ct  = (const float*)d_in[5];
  const float* crt = (const float*)d_in[6];
  const int*   f   = (const int*)d_in[7];
  float* out = (float*)d_out;
  char* ws = (char*)d_ws;

  float4*   verts = (float4*)(ws + OFF_VERTS);
  float*    zbU   = (float*)(ws + OFF_ZBU);
  float*    zbS   = (float*)(ws + OFF_ZBS);
  float4*   bbS   = (float4*)(ws + OFF_BBS);
  float4*   gmS   = (float4*)(ws + OFF_GMS);
  int*      oiS   = (int*)(ws + OFF_OIS);
  int*      inv   = (int*)(ws + OFF_INV);
  unsigned* chdr  = (unsigned*)(ws + OFF_CHDR);
  unsigned* cnt   = (unsigned*)(ws + OFF_CNT);
  unsigned* offs  = (unsigned*)(ws + OFF_OFFS);

  hipLaunchKernelGGL(proj_init_kernel, dim3((NB * HW + 255) / 256), dim3(256), 0, stream,
                     v, cf, cc, ct, crt, verts, zbS, bbS, chdr, cnt);
  hipLaunchKernelGGL(zb_kernel, dim3((NB * NF + 255) / 256), dim3(256), 0, stream,
                     f, verts, zbU, cnt);
  hipLaunchKernelGGL(scan_kernel, dim3(NB), dim3(1024), 0, stream, cnt, offs);
  hipLaunchKernelGGL(scatter_kernel, dim3((NB * NF + 255) / 256), dim3(256), 0, stream,
                     f, verts, zbU, offs, zbS, bbS, gmS, oiS, inv, chdr);
  hipLaunchKernelGGL(suffix_kernel, dim3(NB), dim3(CHDR_STRIDE), 0, stream, chdr);
  hipLaunchKernelGGL(raster_kernel, dim3(W_IMG / 4, H_IMG / 4, NB),
                     dim3(256), 0, stream,
                     chdr, zbS, bbS, gmS, oiS, inv, f, vc, bg, out);
}